// Round 13
// baseline (49.434 us; speedup 1.0000x reference)
//
#include <hip/hip_runtime.h>

// CharacteristicLineEncoder: B=4096, DIM=3, L=300, S=60, P=5, E=128
// Split into two kernels to break the gf phase barrier (R12 lesson: pipes
// don't overlap because no store can issue before the full global-branch
// reduction; measured time ~= sum of pipe times, not max).
//   K1: gf[b,e] = relu(sum_l W_gn[l]*relu(W_ge[e,:]·x[b,:,l]+b_ge[e]) + b_gn)
//       -> d_ws (4096x128 f32 = 2MB)
//   K2: out[b,s,e] = sum_p W_lr[s,p]*relu(W_le[e,:]·x[b,:,5s+p]+b_le[e])
//                    + b_lr[s] + gf[b,e]   (stores stream from t=0)
// Shared mechanics (proven R8-R12): lane owns e-pair {2*lane,2*lane+1} as
// v2f (packed v_pk_fma_f32); x staged in LDS, broadcast ds_read_b128;
// l-indexed weights wave-uniform -> s_load (R6); named accumulators with
// literal indices (R10/rule#20); natural register allocation (R4/R5).

typedef float v2f __attribute__((ext_vector_type(2)));

#define PKFMA(a, b, c) __builtin_elementwise_fma((a), (b), (c))
#define PKRELU(a)      __builtin_elementwise_max((a), (v2f)0.0f)
#define SPLAT(s)       ((v2f)(s))

// ---------------- Kernel 1: global branch -> gf ----------------
__global__ __launch_bounds__(256) void cle_global(
    const float* __restrict__ x,     // [B,3,300]
    const float* __restrict__ W_ge,  // [E,3]
    const float* __restrict__ b_ge,  // [E]
    const float* __restrict__ W_gn,  // [300]
    const float* __restrict__ b_gn,  // [1]
    float* __restrict__ gf_out)      // [B,128] in d_ws
{
    const int tid  = threadIdx.x;
    const int lane = tid & 63;
    const int wq   = __builtin_amdgcn_readfirstlane(tid >> 6);  // 0..3
    const int b    = blockIdx.x;
    const int e0   = lane << 1;

    __shared__ __align__(16) float4 sx4[225];
    __shared__ v2f sgp[4][64];

    if (tid < 225) sx4[tid] = ((const float4*)(x + (size_t)b * 900))[tid];

    const v2f wg0 = {W_ge[e0 * 3 + 0], W_ge[e0 * 3 + 3]};
    const v2f wg1 = {W_ge[e0 * 3 + 1], W_ge[e0 * 3 + 4]};
    const v2f wg2 = {W_ge[e0 * 3 + 2], W_ge[e0 * 3 + 5]};
    const v2f bg  = {b_ge[e0], b_ge[e0 + 1]};
    const float bgn = b_gn[0];

    __syncthreads();

#define GE(cmp) PKRELU(PKFMA(wg2, SPLAT(c2.cmp), PKFMA(wg1, SPLAT(c1.cmp), PKFMA(wg0, SPLAT(c0.cmp), bg))))

    v2f ga0 = SPLAT(0.f), ga1 = SPLAT(0.f), ga2 = SPLAT(0.f), ga3 = SPLAT(0.f);
    {
        const int qb = wq * 20;
        const int nq = (wq < 3) ? 20 : 15;   // SGPR
        for (int g = 0; g < 4; ++g) {
            if (g * 5 < nq) {                // wave-uniform guard
#pragma unroll
                for (int qi = 0; qi < 5; ++qi) {
                    const int qq = qb + g * 5 + qi;
                    const int l4 = qq * 4;   // uniform -> W_gn scalarizes
                    const float4 c0 = sx4[qq], c1 = sx4[75 + qq], c2 = sx4[150 + qq];
                    ga0 = PKFMA(SPLAT(W_gn[l4 + 0]), GE(x), ga0);
                    ga1 = PKFMA(SPLAT(W_gn[l4 + 1]), GE(y), ga1);
                    ga2 = PKFMA(SPLAT(W_gn[l4 + 2]), GE(z), ga2);
                    ga3 = PKFMA(SPLAT(W_gn[l4 + 3]), GE(w), ga3);
                }
            }
        }
    }
    sgp[wq][lane] = (ga0 + ga1) + (ga2 + ga3);
    __syncthreads();

    if (wq == 0) {
        const v2f p0 = sgp[0][lane], p1 = sgp[1][lane];
        const v2f p2 = sgp[2][lane], p3 = sgp[3][lane];
        const v2f gf = PKRELU(((p0 + p1) + (p2 + p3)) + SPLAT(bgn));
        ((v2f*)gf_out)[(size_t)b * 64 + lane] = gf;
    }
}

// ---------------- Kernel 2: local branch + gf, streaming stores ----------------
__global__ __launch_bounds__(256) void cle_local(
    const float* __restrict__ x,     // [B,3,300]
    const float* __restrict__ W_le,  // [E,3]
    const float* __restrict__ b_le,  // [E]
    const float* __restrict__ W_lr,  // [300]
    const float* __restrict__ b_lr,  // [60]
    const float* __restrict__ gf_in, // [B,128] in d_ws
    float* __restrict__ out)         // [B,60,128]
{
    const int tid  = threadIdx.x;
    const int lane = tid & 63;
    const int wq   = __builtin_amdgcn_readfirstlane(tid >> 6);  // 0..3
    const int b    = blockIdx.x;
    const int e0   = lane << 1;

    __shared__ __align__(16) float4 sx4[225];

    if (tid < 225) sx4[tid] = ((const float4*)(x + (size_t)b * 900))[tid];

    // issue gf load early (independent of LDS), L2-hot (written by K1)
    const v2f gf = ((const v2f*)gf_in)[(size_t)b * 64 + lane];

    const v2f wl0 = {W_le[e0 * 3 + 0], W_le[e0 * 3 + 3]};
    const v2f wl1 = {W_le[e0 * 3 + 1], W_le[e0 * 3 + 4]};
    const v2f wl2 = {W_le[e0 * 3 + 2], W_le[e0 * 3 + 5]};
    const v2f bl  = {b_le[e0], b_le[e0 + 1]};

    __syncthreads();

#define LE(cmp) PKRELU(PKFMA(wl2, SPLAT(c2.cmp), PKFMA(wl1, SPLAT(c1.cmp), PKFMA(wl0, SPLAT(c0.cmp), bl))))
#define DOQ(qi, A0, A1, A2, A3)                                                \
    {                                                                          \
        const int qq = q0 + (qi);                                              \
        const int lw = qq * 4;            /* uniform -> W_lr scalarizes */     \
        const float4 c0 = sx4[qq], c1 = sx4[75 + qq], c2 = sx4[150 + qq];      \
        A0 = PKFMA(SPLAT(W_lr[lw + 0]), LE(x), A0);                            \
        A1 = PKFMA(SPLAT(W_lr[lw + 1]), LE(y), A1);                            \
        A2 = PKFMA(SPLAT(W_lr[lw + 2]), LE(z), A2);                            \
        A3 = PKFMA(SPLAT(W_lr[lw + 3]), LE(w), A3);                            \
    }

    v2f* ob2 = (v2f*)(out + (size_t)b * (60 * 128)) + lane;   // + s*64
    {
        const int ng = (wq < 3) ? 4 : 3;     // SGPR: groups of 4 regions (5 quads)
        for (int g = 0; g < 4; ++g) {
            if (g < ng) {                    // wave-uniform guard
                const int q0 = wq * 20 + g * 5;
                v2f a0 = SPLAT(0.f), a1 = SPLAT(0.f), a2 = SPLAT(0.f), a3 = SPLAT(0.f);
                // element t = 4*qi + comp (l = 80wq + 20g + t), region = t/5
                DOQ(0, a0, a0, a0, a0)   // t 0..3
                DOQ(1, a0, a1, a1, a1)   // t 4..7
                DOQ(2, a1, a1, a2, a2)   // t 8..11
                DOQ(3, a2, a2, a2, a3)   // t 12..15
                DOQ(4, a3, a3, a3, a3)   // t 16..19

                const int s0 = wq * 16 + g * 4;   // uniform -> b_lr scalar
                ob2[(s0 + 0) * 64] = a0 + gf + SPLAT(b_lr[s0 + 0]);
                ob2[(s0 + 1) * 64] = a1 + gf + SPLAT(b_lr[s0 + 1]);
                ob2[(s0 + 2) * 64] = a2 + gf + SPLAT(b_lr[s0 + 2]);
                ob2[(s0 + 3) * 64] = a3 + gf + SPLAT(b_lr[s0 + 3]);
            }
        }
    }
}

extern "C" void kernel_launch(void* const* d_in, const int* in_sizes, int n_in,
                              void* d_out, int out_size, void* d_ws, size_t ws_size,
                              hipStream_t stream) {
    const float* x    = (const float*)d_in[0];
    const float* W_le = (const float*)d_in[1];
    const float* b_le = (const float*)d_in[2];
    const float* W_lr = (const float*)d_in[3];
    const float* b_lr = (const float*)d_in[4];
    const float* W_ge = (const float*)d_in[5];
    const float* b_ge = (const float*)d_in[6];
    const float* W_gn = (const float*)d_in[7];
    const float* b_gn = (const float*)d_in[8];
    float* out = (float*)d_out;
    float* gf  = (float*)d_ws;   // 4096*128*4 B = 2 MB scratch

    cle_global<<<4096, 256, 0, stream>>>(x, W_ge, b_ge, W_gn, b_gn, gf);
    cle_local <<<4096, 256, 0, stream>>>(x, W_le, b_le, W_lr, b_lr, gf, out);
}

// Round 14
// 46.722 us; speedup vs baseline: 1.0580x; 1.0580x over previous
//
#include <hip/hip_runtime.h>

// CharacteristicLineEncoder: B=4096, DIM=3, L=300, S=60, P=5, E=128
// out[b,s,e] = sum_p W_lr[s,p]*relu(W_le[e,:]·x[b,:,5s+p] + b_le[e]) + b_lr[s]
//            + relu( sum_l W_gn[l]*relu(W_ge[e,:]·x[b,:,l] + b_ge[e]) + b_gn )
//
// Model fitting R2..R13: the wall is the per-CU LDS pipe at ~12cyc per
// broadcast ds_read_b128; all prior designs read each x-quad >= twice.
// This kernel: FUSED single sweep, each quad read ONCE (225 b128/block).
// 320 threads = 5 waves per b; wave w owns exactly 12 regions = 60 l =
// 15 quads (quad-aligned, perfectly balanced, no guards). Lane owns e-pair
// {2*lane,2*lane+1} as v2f -> packed v_pk_fma_f32 (R12). 12 NAMED v2f
// local accumulators, literal indices only (R10 lesson / rule #20);
// l-indexed weights via wave-uniform s_load (R6 lesson: wq through
// readfirstlane); natural register allocation, no min-waves arg (R4/R5).

typedef float v2f __attribute__((ext_vector_type(2)));

#define PKFMA(a, b, c) __builtin_elementwise_fma((a), (b), (c))
#define PKRELU(a)      __builtin_elementwise_max((a), (v2f)0.0f)
#define SPLAT(s)       ((v2f)(s))

__global__ __launch_bounds__(320) void cle_kernel(
    const float* __restrict__ x,     // [B,3,300]
    const float* __restrict__ W_le,  // [E,3]
    const float* __restrict__ b_le,  // [E]
    const float* __restrict__ W_lr,  // [300]
    const float* __restrict__ b_lr,  // [60]
    const float* __restrict__ W_ge,  // [E,3]
    const float* __restrict__ b_ge,  // [E]
    const float* __restrict__ W_gn,  // [300]
    const float* __restrict__ b_gn,  // [1]
    float* __restrict__ out)         // [B,60,128]
{
    const int tid  = threadIdx.x;
    const int lane = tid & 63;
    const int wq   = __builtin_amdgcn_readfirstlane(tid >> 6);  // wave 0..4, SGPR
    const int b    = blockIdx.x;
    const int e0   = lane << 1;      // this lane's e-pair

    __shared__ __align__(16) float4 sx4[225];  // x[b]: channel c, quad j at [c*75+j]
    __shared__ v2f sgp[5][64];                 // per-wave global-branch partials

    // ---- stage x[b] (3.6 KB), coalesced float4 ----
    if (tid < 225) sx4[tid] = ((const float4*)(x + (size_t)b * 900))[tid];

    // per-lane packed (e0,e1) weights
    const v2f wg0 = {W_ge[e0 * 3 + 0], W_ge[e0 * 3 + 3]};
    const v2f wg1 = {W_ge[e0 * 3 + 1], W_ge[e0 * 3 + 4]};
    const v2f wg2 = {W_ge[e0 * 3 + 2], W_ge[e0 * 3 + 5]};
    const v2f bg  = {b_ge[e0], b_ge[e0 + 1]};
    const v2f wl0 = {W_le[e0 * 3 + 0], W_le[e0 * 3 + 3]};
    const v2f wl1 = {W_le[e0 * 3 + 1], W_le[e0 * 3 + 4]};
    const v2f wl2 = {W_le[e0 * 3 + 2], W_le[e0 * 3 + 5]};
    const v2f bl  = {b_le[e0], b_le[e0 + 1]};
    const float bgn = b_gn[0];

    __syncthreads();

#define GE(cmp) PKRELU(PKFMA(wg2, SPLAT(c2.cmp), PKFMA(wg1, SPLAT(c1.cmp), PKFMA(wg0, SPLAT(c0.cmp), bg))))
#define LE(cmp) PKRELU(PKFMA(wl2, SPLAT(c2.cmp), PKFMA(wl1, SPLAT(c1.cmp), PKFMA(wl0, SPLAT(c0.cmp), bl))))

    // global-branch chains (2 to break the dep chain, packed)
    v2f ga0 = SPLAT(0.f), ga1 = SPLAT(0.f);
    // 12 local accumulators, NAMED, literal indices only
    v2f A00 = SPLAT(0.f), A01 = SPLAT(0.f), A02 = SPLAT(0.f), A03 = SPLAT(0.f);
    v2f A10 = SPLAT(0.f), A11 = SPLAT(0.f), A12 = SPLAT(0.f), A13 = SPLAT(0.f);
    v2f A20 = SPLAT(0.f), A21 = SPLAT(0.f), A22 = SPLAT(0.f), A23 = SPLAT(0.f);

    // one quad = 4 l: 3 broadcast ds_read_b128, feed BOTH branches
#define DOQ(qi, A0, A1, A2, A3)                                                \
    {                                                                          \
        const int qq = q0 + (qi);                                              \
        const int lw = qq * 4;            /* uniform -> s_load */              \
        const float4 c0 = sx4[qq], c1 = sx4[75 + qq], c2 = sx4[150 + qq];      \
        ga0 = PKFMA(SPLAT(W_gn[lw + 0]), GE(x), ga0);                          \
        ga1 = PKFMA(SPLAT(W_gn[lw + 1]), GE(y), ga1);                          \
        ga0 = PKFMA(SPLAT(W_gn[lw + 2]), GE(z), ga0);                          \
        ga1 = PKFMA(SPLAT(W_gn[lw + 3]), GE(w), ga1);                          \
        A0 = PKFMA(SPLAT(W_lr[lw + 0]), LE(x), A0);                            \
        A1 = PKFMA(SPLAT(W_lr[lw + 1]), LE(y), A1);                            \
        A2 = PKFMA(SPLAT(W_lr[lw + 2]), LE(z), A2);                            \
        A3 = PKFMA(SPLAT(W_lr[lw + 3]), LE(w), A3);                            \
    }

    // wave wq owns quads 15wq..15wq+14 = regions 12wq..12wq+11, 3 groups
    // element t = 4*qi + comp (l = 60wq + 20g + t), region = 4g + t/5
    {
        const int q0 = wq * 15;          // group 0: regions 12wq+0..3
        DOQ(0, A00, A00, A00, A00)       // t 0..3
        DOQ(1, A00, A01, A01, A01)       // t 4..7
        DOQ(2, A01, A01, A02, A02)       // t 8..11
        DOQ(3, A02, A02, A02, A03)       // t 12..15
        DOQ(4, A03, A03, A03, A03)       // t 16..19
    }
    {
        const int q0 = wq * 15 + 5;      // group 1: regions 12wq+4..7
        DOQ(0, A10, A10, A10, A10)
        DOQ(1, A10, A11, A11, A11)
        DOQ(2, A11, A11, A12, A12)
        DOQ(3, A12, A12, A12, A13)
        DOQ(4, A13, A13, A13, A13)
    }
    {
        const int q0 = wq * 15 + 10;     // group 2: regions 12wq+8..11
        DOQ(0, A20, A20, A20, A20)
        DOQ(1, A20, A21, A21, A21)
        DOQ(2, A21, A21, A22, A22)
        DOQ(3, A22, A22, A22, A23)
        DOQ(4, A23, A23, A23, A23)
    }

    // combine global-branch partials across the 5 waves
    sgp[wq][lane] = ga0 + ga1;
    __syncthreads();

    v2f gf;
    {
        const v2f p0 = sgp[0][lane], p1 = sgp[1][lane], p2 = sgp[2][lane];
        const v2f p3 = sgp[3][lane], p4 = sgp[4][lane];
        gf = PKRELU((((p0 + p1) + (p2 + p3)) + p4) + SPLAT(bgn));
    }

    // ---- stores: wave wq owns regions s0 = 12wq .. 12wq+11 ----
    v2f* ob2 = (v2f*)(out + (size_t)b * (60 * 128)) + lane;   // + s*64
    const int s0 = wq * 12;                  // uniform -> b_lr scalar
    ob2[(s0 +  0) * 64] = A00 + gf + SPLAT(b_lr[s0 +  0]);
    ob2[(s0 +  1) * 64] = A01 + gf + SPLAT(b_lr[s0 +  1]);
    ob2[(s0 +  2) * 64] = A02 + gf + SPLAT(b_lr[s0 +  2]);
    ob2[(s0 +  3) * 64] = A03 + gf + SPLAT(b_lr[s0 +  3]);
    ob2[(s0 +  4) * 64] = A10 + gf + SPLAT(b_lr[s0 +  4]);
    ob2[(s0 +  5) * 64] = A11 + gf + SPLAT(b_lr[s0 +  5]);
    ob2[(s0 +  6) * 64] = A12 + gf + SPLAT(b_lr[s0 +  6]);
    ob2[(s0 +  7) * 64] = A13 + gf + SPLAT(b_lr[s0 +  7]);
    ob2[(s0 +  8) * 64] = A20 + gf + SPLAT(b_lr[s0 +  8]);
    ob2[(s0 +  9) * 64] = A21 + gf + SPLAT(b_lr[s0 +  9]);
    ob2[(s0 + 10) * 64] = A22 + gf + SPLAT(b_lr[s0 + 10]);
    ob2[(s0 + 11) * 64] = A23 + gf + SPLAT(b_lr[s0 + 11]);
}

extern "C" void kernel_launch(void* const* d_in, const int* in_sizes, int n_in,
                              void* d_out, int out_size, void* d_ws, size_t ws_size,
                              hipStream_t stream) {
    const float* x    = (const float*)d_in[0];
    const float* W_le = (const float*)d_in[1];
    const float* b_le = (const float*)d_in[2];
    const float* W_lr = (const float*)d_in[3];
    const float* b_lr = (const float*)d_in[4];
    const float* W_ge = (const float*)d_in[5];
    const float* b_ge = (const float*)d_in[6];
    const float* W_gn = (const float*)d_in[7];
    const float* b_gn = (const float*)d_in[8];
    float* out = (float*)d_out;

    cle_kernel<<<4096, 320, 0, stream>>>(x, W_le, b_le, W_lr, b_lr,
                                         W_ge, b_ge, W_gn, b_gn, out);
}

// Round 15
// 46.354 us; speedup vs baseline: 1.0664x; 1.0079x over previous
//
#include <hip/hip_runtime.h>

// CharacteristicLineEncoder: B=4096, DIM=3, L=300, S=60, P=5, E=128
// out[b,s,e] = sum_p W_lr[s,p]*relu(W_le[e,:]·x[b,:,5s+p] + b_le[e]) + b_lr[s]
//            + relu( sum_l W_gn[l]*relu(W_ge[e,:]·x[b,:,l] + b_ge[e]) + b_gn )
//
// R14 structure (fused single sweep, 5 balanced waves, packed v2f math)
// but x delivered via WAVE-UNIFORM SCALAR LOADS (s_load) instead of LDS
// broadcast: x[b,*,l] addresses are uniform (b=blockIdx, l=loop consts,
// wq readfirstlane'd), same mechanism that scalarizes the weights (R3/R11:
// SGPR=80). Removes all 225 ds_read_b128 + staging + its barrier; LDS
// shrinks to the 2.5KB gf exchange. R14 budget showed pipes summing, not
// overlapping, with every wave stalled on lgkm/LDS — this moves x to the
// scalar cache pipe. Named accumulators, literal indices (rule #20);
// natural register allocation, no min-waves arg (R4/R5 lesson).

typedef float v2f __attribute__((ext_vector_type(2)));

#define PKFMA(a, b, c) __builtin_elementwise_fma((a), (b), (c))
#define PKRELU(a)      __builtin_elementwise_max((a), (v2f)0.0f)
#define SPLAT(s)       ((v2f)(s))

__global__ __launch_bounds__(320) void cle_kernel(
    const float* __restrict__ x,     // [B,3,300]
    const float* __restrict__ W_le,  // [E,3]
    const float* __restrict__ b_le,  // [E]
    const float* __restrict__ W_lr,  // [300]
    const float* __restrict__ b_lr,  // [60]
    const float* __restrict__ W_ge,  // [E,3]
    const float* __restrict__ b_ge,  // [E]
    const float* __restrict__ W_gn,  // [300]
    const float* __restrict__ b_gn,  // [1]
    float* __restrict__ out)         // [B,60,128]
{
    const int tid  = threadIdx.x;
    const int lane = tid & 63;
    const int wq   = __builtin_amdgcn_readfirstlane(tid >> 6);  // wave 0..4, SGPR
    const int b    = blockIdx.x;
    const int e0   = lane << 1;      // this lane's e-pair

    __shared__ v2f sgp[5][64];       // per-wave global-branch partials (2.5 KB)

    const float* __restrict__ xb = x + (size_t)b * 900;   // uniform base

    // per-lane packed (e0,e1) weights
    const v2f wg0 = {W_ge[e0 * 3 + 0], W_ge[e0 * 3 + 3]};
    const v2f wg1 = {W_ge[e0 * 3 + 1], W_ge[e0 * 3 + 4]};
    const v2f wg2 = {W_ge[e0 * 3 + 2], W_ge[e0 * 3 + 5]};
    const v2f bg  = {b_ge[e0], b_ge[e0 + 1]};
    const v2f wl0 = {W_le[e0 * 3 + 0], W_le[e0 * 3 + 3]};
    const v2f wl1 = {W_le[e0 * 3 + 1], W_le[e0 * 3 + 4]};
    const v2f wl2 = {W_le[e0 * 3 + 2], W_le[e0 * 3 + 5]};
    const v2f bl  = {b_le[e0], b_le[e0 + 1]};
    const float bgn = b_gn[0];

    // global-branch chains (2, packed)
    v2f ga0 = SPLAT(0.f), ga1 = SPLAT(0.f);
    // 12 local accumulators, NAMED, literal indices only
    v2f A00 = SPLAT(0.f), A01 = SPLAT(0.f), A02 = SPLAT(0.f), A03 = SPLAT(0.f);
    v2f A10 = SPLAT(0.f), A11 = SPLAT(0.f), A12 = SPLAT(0.f), A13 = SPLAT(0.f);
    v2f A20 = SPLAT(0.f), A21 = SPLAT(0.f), A22 = SPLAT(0.f), A23 = SPLAT(0.f);

#define GEj(j) PKRELU(PKFMA(wg2, SPLAT(c2##j), PKFMA(wg1, SPLAT(c1##j), PKFMA(wg0, SPLAT(c0##j), bg))))
#define LEj(j) PKRELU(PKFMA(wl2, SPLAT(c2##j), PKFMA(wl1, SPLAT(c1##j), PKFMA(wl0, SPLAT(c0##j), bl))))

    // one quad = 4 l: 12 uniform scalar x-loads (s_load), feed BOTH branches
#define DOQ(qi, A0, A1, A2, A3)                                                \
    {                                                                          \
        const int lq = lbase + (qi) * 4;     /* uniform */                     \
        const float c00 = xb[lq + 0],   c01 = xb[lq + 1];                      \
        const float c02 = xb[lq + 2],   c03 = xb[lq + 3];                      \
        const float c10 = xb[300 + lq + 0], c11 = xb[300 + lq + 1];            \
        const float c12 = xb[300 + lq + 2], c13 = xb[300 + lq + 3];            \
        const float c20 = xb[600 + lq + 0], c21 = xb[600 + lq + 1];            \
        const float c22 = xb[600 + lq + 2], c23 = xb[600 + lq + 3];            \
        ga0 = PKFMA(SPLAT(W_gn[lq + 0]), GEj(0), ga0);                         \
        ga1 = PKFMA(SPLAT(W_gn[lq + 1]), GEj(1), ga1);                         \
        ga0 = PKFMA(SPLAT(W_gn[lq + 2]), GEj(2), ga0);                         \
        ga1 = PKFMA(SPLAT(W_gn[lq + 3]), GEj(3), ga1);                         \
        A0 = PKFMA(SPLAT(W_lr[lq + 0]), LEj(0), A0);                           \
        A1 = PKFMA(SPLAT(W_lr[lq + 1]), LEj(1), A1);                           \
        A2 = PKFMA(SPLAT(W_lr[lq + 2]), LEj(2), A2);                           \
        A3 = PKFMA(SPLAT(W_lr[lq + 3]), LEj(3), A3);                           \
    }

    // wave wq owns l = 60wq .. 60wq+59 = regions 12wq..12wq+11, 3 groups
    // element t = 4*qi + j (l = 60wq + 20g + t), region = 4g + t/5
    {
        const int lbase = wq * 60;           // group 0: regions 12wq+0..3
        DOQ(0, A00, A00, A00, A00)           // t 0..3
        DOQ(1, A00, A01, A01, A01)           // t 4..7
        DOQ(2, A01, A01, A02, A02)           // t 8..11
        DOQ(3, A02, A02, A02, A03)           // t 12..15
        DOQ(4, A03, A03, A03, A03)           // t 16..19
    }
    {
        const int lbase = wq * 60 + 20;      // group 1: regions 12wq+4..7
        DOQ(0, A10, A10, A10, A10)
        DOQ(1, A10, A11, A11, A11)
        DOQ(2, A11, A11, A12, A12)
        DOQ(3, A12, A12, A12, A13)
        DOQ(4, A13, A13, A13, A13)
    }
    {
        const int lbase = wq * 60 + 40;      // group 2: regions 12wq+8..11
        DOQ(0, A20, A20, A20, A20)
        DOQ(1, A20, A21, A21, A21)
        DOQ(2, A21, A21, A22, A22)
        DOQ(3, A22, A22, A22, A23)
        DOQ(4, A23, A23, A23, A23)
    }

    // combine global-branch partials across the 5 waves
    sgp[wq][lane] = ga0 + ga1;
    __syncthreads();

    v2f gf;
    {
        const v2f p0 = sgp[0][lane], p1 = sgp[1][lane], p2 = sgp[2][lane];
        const v2f p3 = sgp[3][lane], p4 = sgp[4][lane];
        gf = PKRELU((((p0 + p1) + (p2 + p3)) + p4) + SPLAT(bgn));
    }

    // ---- stores: wave wq owns regions s0 = 12wq .. 12wq+11 ----
    v2f* ob2 = (v2f*)(out + (size_t)b * (60 * 128)) + lane;   // + s*64
    const int s0 = wq * 12;                  // uniform -> b_lr scalar
    ob2[(s0 +  0) * 64] = A00 + gf + SPLAT(b_lr[s0 +  0]);
    ob2[(s0 +  1) * 64] = A01 + gf + SPLAT(b_lr[s0 +  1]);
    ob2[(s0 +  2) * 64] = A02 + gf + SPLAT(b_lr[s0 +  2]);
    ob2[(s0 +  3) * 64] = A03 + gf + SPLAT(b_lr[s0 +  3]);
    ob2[(s0 +  4) * 64] = A10 + gf + SPLAT(b_lr[s0 +  4]);
    ob2[(s0 +  5) * 64] = A11 + gf + SPLAT(b_lr[s0 +  5]);
    ob2[(s0 +  6) * 64] = A12 + gf + SPLAT(b_lr[s0 +  6]);
    ob2[(s0 +  7) * 64] = A13 + gf + SPLAT(b_lr[s0 +  7]);
    ob2[(s0 +  8) * 64] = A20 + gf + SPLAT(b_lr[s0 +  8]);
    ob2[(s0 +  9) * 64] = A21 + gf + SPLAT(b_lr[s0 +  9]);
    ob2[(s0 + 10) * 64] = A22 + gf + SPLAT(b_lr[s0 + 10]);
    ob2[(s0 + 11) * 64] = A23 + gf + SPLAT(b_lr[s0 + 11]);
}

extern "C" void kernel_launch(void* const* d_in, const int* in_sizes, int n_in,
                              void* d_out, int out_size, void* d_ws, size_t ws_size,
                              hipStream_t stream) {
    const float* x    = (const float*)d_in[0];
    const float* W_le = (const float*)d_in[1];
    const float* b_le = (const float*)d_in[2];
    const float* W_lr = (const float*)d_in[3];
    const float* b_lr = (const float*)d_in[4];
    const float* W_ge = (const float*)d_in[5];
    const float* b_ge = (const float*)d_in[6];
    const float* W_gn = (const float*)d_in[7];
    const float* b_gn = (const float*)d_in[8];
    float* out = (float*)d_out;

    cle_kernel<<<4096, 320, 0, stream>>>(x, W_le, b_le, W_lr, b_lr,
                                         W_ge, b_ge, W_gn, b_gn, out);
}